// Round 9
// baseline (694.409 us; speedup 1.0000x reference)
//
#include <hip/hip_runtime.h>
#include <hip/hip_bf16.h>
#include <cstdint>
#include <cstddef>

#define NN 50000
#define RR 4
#define EE 400000
#define TE (RR*EE)
#define HR 12500         // hist bins per range (4 ranges * 12500 = 50000)
#define RN (RR*NN)       // 200000
#define NSEG (NN*RR)     // 200000 (d-major, r-minor segments)
#define SCB2 782         // ceil(NSEG/256)
#define NBK 256          // dst buckets for the partition
#define BKSZ 196         // nodes per bucket (256*196 >= 50000)
#define CHA 4000         // edges per phase-A block (100 chunks/relation)
#define MAXSPAN 12288    // LDS image capacity (avg span ~6250)

using frag_ab = __attribute__((ext_vector_type(8))) short;   // 8 bf16 (4 VGPRs)
using frag_cd = __attribute__((ext_vector_type(4))) float;   // 4 fp32
typedef float f2 __attribute__((ext_vector_type(2)));

static __device__ __forceinline__ unsigned short f2bf(float f) {
    union { float f; unsigned u; } v; v.f = f;
    unsigned r = (v.u + 0x7FFF + ((v.u >> 16) & 1)) >> 16;   // RNE
    return (unsigned short)r;
}
static __device__ __forceinline__ unsigned pack2(float lo, float hi) {
    return (unsigned)f2bf(lo) | ((unsigned)f2bf(hi) << 16);
}

// ---------------- degree histograms: packed 16-bit LDS counters ----------------
__global__ __launch_bounds__(1024) void k_hist(const int* __restrict__ src,
                                               const int* __restrict__ dst,
                                               int* __restrict__ cnt_srcQ,
                                               int* __restrict__ cnt_dstQ) {
    __shared__ unsigned bins[HR / 2];   // 6250 uints = 25 KB
    int combo = blockIdx.x >> 4;
    int range = (blockIdx.x >> 2) & 3;
    int qc    = blockIdx.x & 3;
    int r = combo >> 1;
    int side = combo & 1;
    const int* arr = (side == 0 ? src : dst) + (size_t)r * EE + (size_t)qc * (EE / 4);
    int lo = range * HR;
    for (int i = threadIdx.x; i < HR / 2; i += 1024) bins[i] = 0;
    __syncthreads();
    const int4* a4 = (const int4*)arr;
    for (int i = threadIdx.x; i < EE / 16; i += 1024) {
        int4 v = a4[i];
        int t;
        t = v.x - lo; if ((unsigned)t < (unsigned)HR) atomicAdd(&bins[t >> 1], 1u << ((t & 1) * 16));
        t = v.y - lo; if ((unsigned)t < (unsigned)HR) atomicAdd(&bins[t >> 1], 1u << ((t & 1) * 16));
        t = v.z - lo; if ((unsigned)t < (unsigned)HR) atomicAdd(&bins[t >> 1], 1u << ((t & 1) * 16));
        t = v.w - lo; if ((unsigned)t < (unsigned)HR) atomicAdd(&bins[t >> 1], 1u << ((t & 1) * 16));
    }
    __syncthreads();
    int* outp = (side == 0 ? cnt_srcQ : cnt_dstQ) + (size_t)qc * RN + (size_t)r * NN + lo;
    for (int i = threadIdx.x; i < HR / 2; i += 1024) {
        unsigned b = bins[i];
        outp[2 * i]     = (int)(b & 0xFFFFu);
        outp[2 * i + 1] = (int)(b >> 16);
    }
}

// sum quarters -> norms ([r*NN+d]) + counts in [d*4+r] layout for the scan
__global__ __launch_bounds__(256) void k_sum_norms(const int* __restrict__ cnt_srcQ,
                                                   const int* __restrict__ cnt_dstQ,
                                                   float* __restrict__ nsrc,
                                                   float* __restrict__ ndst,
                                                   int* __restrict__ cntd2) {
    int i = blockIdx.x * 256 + threadIdx.x;
    if (i >= RN) return;
    int ss = cnt_srcQ[i] + cnt_srcQ[RN + i] + cnt_srcQ[2 * RN + i] + cnt_srcQ[3 * RN + i];
    int ds = cnt_dstQ[i] + cnt_dstQ[RN + i] + cnt_dstQ[2 * RN + i] + cnt_dstQ[3 * RN + i];
    nsrc[i] = 1.0f / sqrtf(fmaxf((float)ss, 1.0f));
    ndst[i] = 1.0f / sqrtf(fmaxf((float)ds, 1.0f));
    int r = i / NN, d = i - r * NN;
    cntd2[d * 4 + r] = ds;
}

// ---------------- 3-phase parallel scan over 200K (d,r) segment counts ----------------
__global__ __launch_bounds__(256) void k_partial(const int* __restrict__ cntd2,
                                                 int* __restrict__ part) {
    __shared__ int s[256];
    int t = threadIdx.x;
    int f = blockIdx.x * 256 + t;
    int v = (f < NSEG) ? cntd2[f] : 0;
    s[t] = v;
    __syncthreads();
    for (int off = 128; off > 0; off >>= 1) {
        if (t < off) s[t] += s[t + off];
        __syncthreads();
    }
    if (t == 0) part[blockIdx.x] = s[0];
}

__global__ __launch_bounds__(1024) void k_scan_small(const int* __restrict__ part,
                                                     int* __restrict__ offs) {
    __shared__ int s[1024];
    int t = threadIdx.x;
    s[t] = (t < SCB2) ? part[t] : 0;
    __syncthreads();
    for (int off = 1; off < 1024; off <<= 1) {
        int v = (t >= off) ? s[t - off] : 0;
        __syncthreads();
        s[t] += v;
        __syncthreads();
    }
    if (t < SCB2) offs[t] = (t == 0) ? 0 : s[t - 1];
}

__global__ __launch_bounds__(256) void k_emit(const int* __restrict__ cntd2,
                                              const int* __restrict__ offs,
                                              int* __restrict__ rp2) {
    __shared__ int s[256];
    int t = threadIdx.x;
    int f = blockIdx.x * 256 + t;
    int v = (f < NSEG) ? cntd2[f] : 0;
    s[t] = v;
    __syncthreads();
    for (int off = 1; off < 256; off <<= 1) {
        int u = (t >= off) ? s[t - off] : 0;
        __syncthreads();
        s[t] += u;
        __syncthreads();
    }
    if (f < NSEG) rp2[f] = offs[blockIdx.x] + s[t] - v;
    if (f == NSEG - 1) rp2[NSEG] = TE;
}

// ---------------- two-phase edge partition ----------------
__global__ __launch_bounds__(256) void k_initg(const int* __restrict__ rp2,
                                               int* __restrict__ gcur) {
    int t = threadIdx.x;
    gcur[t] = rp2[t * BKSZ * 4];
}

// Phase A: multi-split edges into 256 dst-range buckets.
// payload: src(16) | r(2 @16) | dlocal(8 @18)
__global__ __launch_bounds__(256) void k_fillA(const int* __restrict__ src,
                                               const int* __restrict__ dst,
                                               int* __restrict__ gcur,
                                               unsigned* __restrict__ stage) {
    __shared__ int cnt[NBK];
    __shared__ int rcur[NBK];
    int r = blockIdx.y;
    int base_e = blockIdx.x * CHA;
    int t = threadIdx.x;
    cnt[t] = 0;
    __syncthreads();
    const int* dr = dst + (size_t)r * EE;
    const int* sr = src + (size_t)r * EE;
    for (int i = base_e + t; i < base_e + CHA; i += 256) {
        int d = dr[i];
        atomicAdd(&cnt[d / BKSZ], 1);
    }
    __syncthreads();
    rcur[t] = atomicAdd(&gcur[t], cnt[t]);
    __syncthreads();
    for (int i = base_e + t; i < base_e + CHA; i += 256) {
        int d = dr[i];
        int s = sr[i];
        int b = d / BKSZ;
        int dl = d - b * BKSZ;
        int pos = atomicAdd(&rcur[b], 1);
        stage[pos] = (unsigned)s | ((unsigned)r << 16) | ((unsigned)dl << 18);
    }
}

// Phase B: one block per bucket; order into exact (d,r) segments via LDS image.
__global__ __launch_bounds__(256) void k_fillB(const unsigned* __restrict__ stage,
                                               const int* __restrict__ rp2,
                                               unsigned short* __restrict__ eb) {
    __shared__ unsigned short img[MAXSPAN];
    __shared__ int lcur[BKSZ * 4];
    int b = blockIdx.x;
    int t = threadIdx.x;
    int node0 = b * BKSZ;
    int nodes = min(BKSZ, NN - node0);
    int nseg_local = nodes * 4;
    int segbase = node0 * 4;
    for (int i = t; i < nseg_local; i += 256) lcur[i] = rp2[segbase + i];
    __syncthreads();
    int S0 = lcur[0];
    int S1 = rp2[segbase + nseg_local];
    int span = S1 - S0;
    if (span <= MAXSPAN) {
        for (int i = S0 + t; i < S1; i += 256) {
            unsigned w = stage[i];
            int seg = (int)((w >> 18) & 0xFF) * 4 + (int)((w >> 16) & 3);
            int pos = atomicAdd(&lcur[seg], 1);
            img[pos - S0] = (unsigned short)(w & 0xFFFF);
        }
        __syncthreads();
        for (int i = t; i < span; i += 256) eb[S0 + i] = img[i];
    } else {
        for (int i = S0 + t; i < S1; i += 256) {
            unsigned w = stage[i];
            int seg = (int)((w >> 18) & 0xFF) * 4 + (int)((w >> 16) & 3);
            int pos = atomicAdd(&lcur[seg], 1);
            eb[pos] = (unsigned short)(w & 0xFFFF);
        }
    }
}

// ---------------- converts ----------------
__global__ __launch_bounds__(256) void k_cvt_x(const float4* __restrict__ x4,
                                               uint2* __restrict__ o, int n4) {
    int i = blockIdx.x * 256 + threadIdx.x;
    if (i >= n4) return;
    float4 v = x4[i];
    o[i] = make_uint2(pack2(v.x, v.y), pack2(v.z, v.w));
}

// Bt[n][k] = bf16(basis[k][n]); basis flat [256][BN]
__global__ __launch_bounds__(256) void k_cvt_bt(const float* __restrict__ B,
                                                unsigned short* __restrict__ Bt, int BN) {
    int o = blockIdx.x * 256 + threadIdx.x;
    if (o >= BN * 256) return;
    int k = o & 255, n = o >> 8;
    Bt[o] = f2bf(B[k * BN + n]);
}

// ---------------- aggregation: flat edge loop, quarter-wave per edge ----------------
// hb4: bf16 rows of 128 ch = 16 uint4. eb: ushort src, r-sorted within each node
// span so r(e) = (e>=b1)+(e>=b2)+(e>=b3). Weights from 8 per-wave folded regs.
__global__ __launch_bounds__(256) void k_agg(const uint4* __restrict__ hb4,
                                             const int* __restrict__ rp2,
                                             const unsigned short* __restrict__ eb,
                                             const float* __restrict__ nsrc,
                                             const float* __restrict__ ndst,
                                             const float* __restrict__ coeff,
                                             uint2* __restrict__ Mb2) {
    int wave = (blockIdx.x * 256 + threadIdx.x) >> 6;
    int lane = threadIdx.x & 63;
    if (wave >= NN) return;
    int q = lane >> 4, hl = lane & 15;

    int4 sg = *(const int4*)&rp2[wave * 4];
    int e0 = sg.x, b1 = sg.y, b2 = sg.z, b3 = sg.w;
    int e1 = rp2[wave * 4 + 4];

    float cA[RR], cB[RR];
#pragma unroll
    for (int r = 0; r < RR; r++) {
        float nd = ndst[r * NN + wave];
        cA[r] = coeff[r * 2 + 0] * nd;
        cB[r] = coeff[r * 2 + 1] * nd;
    }

    f2 a0[4], a1[4];
#pragma unroll
    for (int i = 0; i < 4; i++) { a0[i] = (f2){0.f, 0.f}; a1[i] = (f2){0.f, 0.f}; }

    int e = e0;
    // main: 16 edges/iter, 4 per quarter, 4 gather chains in flight
    for (; e + 15 < e1; e += 16) {
        int E[4] = {e + q, e + 4 + q, e + 8 + q, e + 12 + q};
        int s[4], r[4];
#pragma unroll
        for (int k = 0; k < 4; k++) {
            s[k] = eb[E[k]];
            r[k] = (E[k] >= b1) + (E[k] >= b2) + (E[k] >= b3);
        }
        float ns[4];
#pragma unroll
        for (int k = 0; k < 4; k++) ns[k] = nsrc[r[k] * NN + s[k]];
        uint4 h[4];
#pragma unroll
        for (int k = 0; k < 4; k++) h[k] = hb4[(size_t)s[k] * 16 + hl];
#pragma unroll
        for (int k = 0; k < 4; k++) {
            int rr = r[k];
            float wa = (rr == 0 ? cA[0] : rr == 1 ? cA[1] : rr == 2 ? cA[2] : cA[3]) * ns[k];
            float wb = (rr == 0 ? cB[0] : rr == 1 ? cB[1] : rr == 2 ? cB[2] : cB[3]) * ns[k];
            f2 w0 = (f2){wa, wa};
            f2 w1 = (f2){wb, wb};
            unsigned u[4] = {h[k].x, h[k].y, h[k].z, h[k].w};
#pragma unroll
            for (int j = 0; j < 4; j++) {
                f2 hv = (f2){__uint_as_float(u[j] << 16), __uint_as_float(u[j] & 0xFFFF0000u)};
                a0[j] = __builtin_elementwise_fma(w0, hv, a0[j]);
                a1[j] = __builtin_elementwise_fma(w1, hv, a1[j]);
            }
        }
    }
    // masked tail: 4 edges/iter, one per quarter
    for (; e < e1; e += 4) {
        int E = e + q;
        bool act = E < e1;
        int Ec = act ? E : e0;
        int s = eb[Ec];
        int rr = (Ec >= b1) + (Ec >= b2) + (Ec >= b3);
        float ns = act ? nsrc[rr * NN + s] : 0.f;
        uint4 h = hb4[(size_t)s * 16 + hl];
        float wa = (rr == 0 ? cA[0] : rr == 1 ? cA[1] : rr == 2 ? cA[2] : cA[3]) * ns;
        float wb = (rr == 0 ? cB[0] : rr == 1 ? cB[1] : rr == 2 ? cB[2] : cB[3]) * ns;
        f2 w0 = (f2){wa, wa};
        f2 w1 = (f2){wb, wb};
        unsigned u[4] = {h.x, h.y, h.z, h.w};
#pragma unroll
        for (int j = 0; j < 4; j++) {
            f2 hv = (f2){__uint_as_float(u[j] << 16), __uint_as_float(u[j] & 0xFFFF0000u)};
            a0[j] = __builtin_elementwise_fma(w0, hv, a0[j]);
            a1[j] = __builtin_elementwise_fma(w1, hv, a1[j]);
        }
    }

    // cross-quarter reduce (xor 16, then 32): all quarters end with full sums
#pragma unroll
    for (int i = 0; i < 4; i++) {
        a0[i].x += __shfl_xor(a0[i].x, 16, 64); a0[i].x += __shfl_xor(a0[i].x, 32, 64);
        a0[i].y += __shfl_xor(a0[i].y, 16, 64); a0[i].y += __shfl_xor(a0[i].y, 32, 64);
        a1[i].x += __shfl_xor(a1[i].x, 16, 64); a1[i].x += __shfl_xor(a1[i].x, 32, 64);
        a1[i].y += __shfl_xor(a1[i].y, 16, 64); a1[i].y += __shfl_xor(a1[i].y, 32, 64);
    }

    // lane (q,hl): coeff c = q>>1, half h4 = q&1 -> channels hl*8 + h4*4 + 0..3
    int c = q >> 1, h4 = q & 1;
    f2 p0 = c ? a1[h4 * 2] : a0[h4 * 2];
    f2 p1 = c ? a1[h4 * 2 + 1] : a0[h4 * 2 + 1];
    uint2 st;
    st.x = pack2(p0.x, p0.y);
    st.y = pack2(p1.x, p1.y);
    Mb2[(size_t)wave * 64 + c * 32 + hl * 2 + h4] = st;
}

// ---------------- MFMA bf16 GEMM: C[N,BN] = Mb[N,256] @ B[256,BN] ----------------
template <int BN, bool BF16OUT>
__global__ __launch_bounds__(256) void k_gemm(const unsigned short* __restrict__ A,
                                              const unsigned short* __restrict__ Bt,
                                              void* __restrict__ Cout) {
    int wave = threadIdx.x >> 6, lane = threadIdx.x & 63;
    int row0 = blockIdx.x * 64 + wave * 16;
    if (row0 >= NN) return;
    int m = lane & 15, q = lane >> 4;
    const int NT = BN / 16;

    frag_cd acc[NT];
#pragma unroll
    for (int ct = 0; ct < NT; ct++) acc[ct] = (frag_cd){0.f, 0.f, 0.f, 0.f};

    const size_t abase = (size_t)(row0 + m) * 256 + q * 8;
#pragma unroll
    for (int kc = 0; kc < 8; kc++) {
        frag_ab a = *(const frag_ab*)(A + abase + kc * 32);
#pragma unroll
        for (int ct = 0; ct < NT; ct++) {
            frag_ab b = *(const frag_ab*)(Bt + (size_t)(ct * 16 + m) * 256 + kc * 32 + q * 8);
            acc[ct] = __builtin_amdgcn_mfma_f32_16x16x32_bf16(a, b, acc[ct], 0, 0, 0);
        }
    }

#pragma unroll
    for (int ct = 0; ct < NT; ct++) {
#pragma unroll
        for (int i = 0; i < 4; i++) {
            int row = row0 + q * 4 + i;
            int col = ct * 16 + m;
            float v = acc[ct][i];
            if (BF16OUT) {
                v = fmaxf(v, 0.f);
                ((unsigned short*)Cout)[(size_t)row * BN + col] = f2bf(v);
            } else {
                ((float*)Cout)[(size_t)row * BN + col] = v;
            }
        }
    }
}

// ---------------- host ----------------

extern "C" void kernel_launch(void* const* d_in, const int* in_sizes, int n_in,
                              void* d_out, int out_size, void* d_ws, size_t ws_size,
                              hipStream_t stream) {
    const float* x      = (const float*)d_in[0];
    const int*   src    = (const int*)d_in[1];
    const int*   dst    = (const int*)d_in[2];
    const float* basis0 = (const float*)d_in[3];
    const float* coeff0 = (const float*)d_in[4];
    const float* basis1 = (const float*)d_in[5];
    const float* coeff1 = (const float*)d_in[6];
    const float* basis2 = (const float*)d_in[7];
    const float* coeff2 = (const float*)d_in[8];
    float* out = (float*)d_out;

    char* p = (char*)d_ws;
    auto alloc = [&](size_t bytes) {
        char* r = p;
        p += (bytes + 255) & ~(size_t)255;
        return r;
    };
    int*   cnt_srcQ = (int*)alloc((size_t)4 * RN * 4);
    int*   cnt_dstQ = (int*)alloc((size_t)4 * RN * 4);
    float* nsrc     = (float*)alloc((size_t)RN * 4);
    float* ndst     = (float*)alloc((size_t)RN * 4);
    int*   cntd2    = (int*)alloc((size_t)NSEG * 4);
    int*   rp2      = (int*)alloc((size_t)(NSEG + 1) * 4);
    int*   part     = (int*)alloc((size_t)SCB2 * 4);
    int*   offs     = (int*)alloc((size_t)SCB2 * 4);
    int*   gcur     = (int*)alloc((size_t)NBK * 4);
    unsigned* stage = (unsigned*)alloc((size_t)TE * 4);
    unsigned short* eb = (unsigned short*)alloc((size_t)TE * 2);
    unsigned* Mb   = (unsigned*)alloc((size_t)NN * 128 * 4);        // bf16 [N][256]
    unsigned* Hb   = (unsigned*)alloc((size_t)NN * 64 * 4);         // bf16 [N][128]
    unsigned* Xb   = (unsigned*)alloc((size_t)NN * 64 * 4);         // bf16 [N][128]
    unsigned short* Bt0 = (unsigned short*)alloc((size_t)128 * 256 * 2);
    unsigned short* Bt1 = (unsigned short*)alloc((size_t)128 * 256 * 2);
    unsigned short* Bt2 = (unsigned short*)alloc((size_t)64 * 256 * 2);

    // setup
    k_cvt_x<<<(NN * 32 + 255) / 256, 256, 0, stream>>>((const float4*)x, (uint2*)Xb, NN * 32);
    k_cvt_bt<<<(128 * 256 + 255) / 256, 256, 0, stream>>>(basis0, Bt0, 128);
    k_cvt_bt<<<(128 * 256 + 255) / 256, 256, 0, stream>>>(basis1, Bt1, 128);
    k_cvt_bt<<<(64 * 256 + 255) / 256, 256, 0, stream>>>(basis2, Bt2, 64);
    k_hist<<<128, 1024, 0, stream>>>(src, dst, cnt_srcQ, cnt_dstQ);
    k_sum_norms<<<(RN + 255) / 256, 256, 0, stream>>>(cnt_srcQ, cnt_dstQ, nsrc, ndst, cntd2);
    k_partial<<<SCB2, 256, 0, stream>>>(cntd2, part);
    k_scan_small<<<1, 1024, 0, stream>>>(part, offs);
    k_emit<<<SCB2, 256, 0, stream>>>(cntd2, offs, rp2);
    k_initg<<<1, NBK, 0, stream>>>(rp2, gcur);
    k_fillA<<<dim3(EE / CHA, RR), 256, 0, stream>>>(src, dst, gcur, stage);
    k_fillB<<<NBK, 256, 0, stream>>>(stage, rp2, eb);

    int aggBlocks = NN / 4;
    int gemmBlocks = (NN + 63) / 64;   // 782

    // layer 0: Xb -> Mb -> Hb (relu, bf16)
    k_agg<<<aggBlocks, 256, 0, stream>>>((const uint4*)Xb, rp2, eb, nsrc, ndst, coeff0, (uint2*)Mb);
    k_gemm<128, true><<<gemmBlocks, 256, 0, stream>>>((const unsigned short*)Mb, Bt0, Hb);
    // layer 1
    k_agg<<<aggBlocks, 256, 0, stream>>>((const uint4*)Hb, rp2, eb, nsrc, ndst, coeff1, (uint2*)Mb);
    k_gemm<128, true><<<gemmBlocks, 256, 0, stream>>>((const unsigned short*)Mb, Bt1, Hb);
    // layer 2: final, fp32 out, no relu
    k_agg<<<aggBlocks, 256, 0, stream>>>((const uint4*)Hb, rp2, eb, nsrc, ndst, coeff2, (uint2*)Mb);
    k_gemm<64, false><<<gemmBlocks, 256, 0, stream>>>((const unsigned short*)Mb, Bt2, out);
}

// Round 10
// 598.284 us; speedup vs baseline: 1.1607x; 1.1607x over previous
//
#include <hip/hip_runtime.h>
#include <hip/hip_bf16.h>
#include <cstdint>
#include <cstddef>

#define NN 50000
#define RR 4
#define EE 400000
#define TE (RR*EE)
#define HR 12500         // hist bins per range (4 ranges * 12500 = 50000)
#define RN (RR*NN)       // 200000
#define NSEG (NN*RR)     // 200000 (d-major, r-minor segments)
#define SCB2 782         // ceil(NSEG/256)
#define NBK 512          // dst buckets for the partition
#define BKSZ 98          // nodes per bucket (512*98 >= 50000)
#define CHA 4000         // edges per phase-A block (100 chunks/relation)
#define MAXSPAN 4608     // LDS image capacity (avg span ~3136, sd ~56)

using frag_ab = __attribute__((ext_vector_type(8))) short;   // 8 bf16 (4 VGPRs)
using frag_cd = __attribute__((ext_vector_type(4))) float;   // 4 fp32
typedef float f2 __attribute__((ext_vector_type(2)));

static __device__ __forceinline__ unsigned short f2bf(float f) {
    union { float f; unsigned u; } v; v.f = f;
    unsigned r = (v.u + 0x7FFF + ((v.u >> 16) & 1)) >> 16;   // RNE
    return (unsigned short)r;
}
static __device__ __forceinline__ unsigned pack2(float lo, float hi) {
    return (unsigned)f2bf(lo) | ((unsigned)f2bf(hi) << 16);
}

// ---------------- degree histograms: packed 16-bit LDS counters ----------------
__global__ __launch_bounds__(1024) void k_hist(const int* __restrict__ src,
                                               const int* __restrict__ dst,
                                               int* __restrict__ cnt_srcQ,
                                               int* __restrict__ cnt_dstQ) {
    __shared__ unsigned bins[HR / 2];   // 6250 uints = 25 KB
    int combo = blockIdx.x >> 4;
    int range = (blockIdx.x >> 2) & 3;
    int qc    = blockIdx.x & 3;
    int r = combo >> 1;
    int side = combo & 1;
    const int* arr = (side == 0 ? src : dst) + (size_t)r * EE + (size_t)qc * (EE / 4);
    int lo = range * HR;
    for (int i = threadIdx.x; i < HR / 2; i += 1024) bins[i] = 0;
    __syncthreads();
    const int4* a4 = (const int4*)arr;
    for (int i = threadIdx.x; i < EE / 16; i += 1024) {
        int4 v = a4[i];
        int t;
        t = v.x - lo; if ((unsigned)t < (unsigned)HR) atomicAdd(&bins[t >> 1], 1u << ((t & 1) * 16));
        t = v.y - lo; if ((unsigned)t < (unsigned)HR) atomicAdd(&bins[t >> 1], 1u << ((t & 1) * 16));
        t = v.z - lo; if ((unsigned)t < (unsigned)HR) atomicAdd(&bins[t >> 1], 1u << ((t & 1) * 16));
        t = v.w - lo; if ((unsigned)t < (unsigned)HR) atomicAdd(&bins[t >> 1], 1u << ((t & 1) * 16));
    }
    __syncthreads();
    int* outp = (side == 0 ? cnt_srcQ : cnt_dstQ) + (size_t)qc * RN + (size_t)r * NN + lo;
    for (int i = threadIdx.x; i < HR / 2; i += 1024) {
        unsigned b = bins[i];
        outp[2 * i]     = (int)(b & 0xFFFFu);
        outp[2 * i + 1] = (int)(b >> 16);
    }
}

// sum quarters -> norms ([r*NN+d]) + counts in [d*4+r] layout for the scan
__global__ __launch_bounds__(256) void k_sum_norms(const int* __restrict__ cnt_srcQ,
                                                   const int* __restrict__ cnt_dstQ,
                                                   float* __restrict__ nsrc,
                                                   float* __restrict__ ndst,
                                                   int* __restrict__ cntd2) {
    int i = blockIdx.x * 256 + threadIdx.x;
    if (i >= RN) return;
    int ss = cnt_srcQ[i] + cnt_srcQ[RN + i] + cnt_srcQ[2 * RN + i] + cnt_srcQ[3 * RN + i];
    int ds = cnt_dstQ[i] + cnt_dstQ[RN + i] + cnt_dstQ[2 * RN + i] + cnt_dstQ[3 * RN + i];
    nsrc[i] = 1.0f / sqrtf(fmaxf((float)ss, 1.0f));
    ndst[i] = 1.0f / sqrtf(fmaxf((float)ds, 1.0f));
    int r = i / NN, d = i - r * NN;
    cntd2[d * 4 + r] = ds;
}

// ---------------- 3-phase parallel scan over 200K (d,r) segment counts ----------------
__global__ __launch_bounds__(256) void k_partial(const int* __restrict__ cntd2,
                                                 int* __restrict__ part) {
    __shared__ int s[256];
    int t = threadIdx.x;
    int f = blockIdx.x * 256 + t;
    int v = (f < NSEG) ? cntd2[f] : 0;
    s[t] = v;
    __syncthreads();
    for (int off = 128; off > 0; off >>= 1) {
        if (t < off) s[t] += s[t + off];
        __syncthreads();
    }
    if (t == 0) part[blockIdx.x] = s[0];
}

__global__ __launch_bounds__(1024) void k_scan_small(const int* __restrict__ part,
                                                     int* __restrict__ offs) {
    __shared__ int s[1024];
    int t = threadIdx.x;
    s[t] = (t < SCB2) ? part[t] : 0;
    __syncthreads();
    for (int off = 1; off < 1024; off <<= 1) {
        int v = (t >= off) ? s[t - off] : 0;
        __syncthreads();
        s[t] += v;
        __syncthreads();
    }
    if (t < SCB2) offs[t] = (t == 0) ? 0 : s[t - 1];
}

__global__ __launch_bounds__(256) void k_emit(const int* __restrict__ cntd2,
                                              const int* __restrict__ offs,
                                              int* __restrict__ rp2) {
    __shared__ int s[256];
    int t = threadIdx.x;
    int f = blockIdx.x * 256 + t;
    int v = (f < NSEG) ? cntd2[f] : 0;
    s[t] = v;
    __syncthreads();
    for (int off = 1; off < 256; off <<= 1) {
        int u = (t >= off) ? s[t - off] : 0;
        __syncthreads();
        s[t] += u;
        __syncthreads();
    }
    if (f < NSEG) rp2[f] = offs[blockIdx.x] + s[t] - v;
    if (f == NSEG - 1) rp2[NSEG] = TE;
}

// ---------------- two-phase edge partition ----------------
__global__ __launch_bounds__(256) void k_initg(const int* __restrict__ rp2,
                                               int* __restrict__ gcur) {
    int i = blockIdx.x * 256 + threadIdx.x;
    if (i < NBK) gcur[i] = rp2[min(i * BKSZ * 4, NSEG)];
}

// Phase A: multi-split edges into 512 dst-range buckets.
// payload: src(16) | r(2 @16) | dlocal(7 @18)
__global__ __launch_bounds__(256) void k_fillA(const int* __restrict__ src,
                                               const int* __restrict__ dst,
                                               int* __restrict__ gcur,
                                               unsigned* __restrict__ stage) {
    __shared__ int cnt[NBK];
    __shared__ int rcur[NBK];
    int r = blockIdx.y;
    int base_e = blockIdx.x * CHA;
    int t = threadIdx.x;
    for (int i = t; i < NBK; i += 256) cnt[i] = 0;
    __syncthreads();
    const int* dr = dst + (size_t)r * EE;
    const int* sr = src + (size_t)r * EE;
    for (int i = base_e + t; i < base_e + CHA; i += 256) {
        int d = dr[i];
        atomicAdd(&cnt[d / BKSZ], 1);
    }
    __syncthreads();
    for (int i = t; i < NBK; i += 256) rcur[i] = atomicAdd(&gcur[i], cnt[i]);
    __syncthreads();
    for (int i = base_e + t; i < base_e + CHA; i += 256) {
        int d = dr[i];
        int s = sr[i];
        int b = d / BKSZ;
        int dl = d - b * BKSZ;
        int pos = atomicAdd(&rcur[b], 1);
        stage[pos] = (unsigned)s | ((unsigned)r << 16) | ((unsigned)dl << 18);
    }
}

// Phase B: one block per bucket; order into exact (d,r) segments via LDS image
// and emit the full 8B edge record {src|r<<16, fp32 w=ns*nd} (layer-invariant).
__global__ __launch_bounds__(256) void k_fillB(const unsigned* __restrict__ stage,
                                               const int* __restrict__ rp2,
                                               const float* __restrict__ nsrc,
                                               const float* __restrict__ ndst,
                                               uint2* __restrict__ ed) {
    __shared__ unsigned imgU[MAXSPAN];   // src | r<<16
    __shared__ float imgW[MAXSPAN];      // ns*nd
    __shared__ int lcur[BKSZ * 4];
    __shared__ float ndL[BKSZ * 4];
    int b = blockIdx.x;
    int t = threadIdx.x;
    int node0 = b * BKSZ;
    if (node0 >= NN) return;
    int nodes = min(BKSZ, NN - node0);
    int nseg_local = nodes * 4;
    int segbase = node0 * 4;
    for (int i = t; i < nseg_local; i += 256) {
        lcur[i] = rp2[segbase + i];
        ndL[i] = ndst[(i & 3) * NN + node0 + (i >> 2)];
    }
    __syncthreads();
    int S0 = rp2[segbase];
    int S1 = rp2[segbase + nseg_local];
    int span = S1 - S0;
    if (span <= MAXSPAN) {
        for (int i = S0 + t; i < S1; i += 256) {
            unsigned w = stage[i];
            int s = (int)(w & 0xFFFFu);
            int r = (int)((w >> 16) & 3u);
            int dl = (int)(w >> 18);
            int seg = dl * 4 + r;
            int pos = atomicAdd(&lcur[seg], 1);
            int idx = pos - S0;
            imgU[idx] = w & 0x3FFFFu;            // src | r<<16
            imgW[idx] = nsrc[r * NN + s] * ndL[seg];
        }
        __syncthreads();
        for (int i = t; i < span; i += 256)
            ed[S0 + i] = make_uint2(imgU[i], __float_as_uint(imgW[i]));
    } else {  // overflow fallback (statistically unreachable)
        for (int i = S0 + t; i < S1; i += 256) {
            unsigned w = stage[i];
            int s = (int)(w & 0xFFFFu);
            int r = (int)((w >> 16) & 3u);
            int dl = (int)(w >> 18);
            int seg = dl * 4 + r;
            int pos = atomicAdd(&lcur[seg], 1);
            ed[pos] = make_uint2(w & 0x3FFFFu,
                                 __float_as_uint(nsrc[r * NN + s] * ndL[seg]));
        }
    }
}

// ---------------- converts ----------------
__global__ __launch_bounds__(256) void k_cvt_x(const float4* __restrict__ x4,
                                               uint2* __restrict__ o, int n4) {
    int i = blockIdx.x * 256 + threadIdx.x;
    if (i >= n4) return;
    float4 v = x4[i];
    o[i] = make_uint2(pack2(v.x, v.y), pack2(v.z, v.w));
}

// Bt[n][k] = bf16(basis[k][n]); basis flat [256][BN]
__global__ __launch_bounds__(256) void k_cvt_bt(const float* __restrict__ B,
                                                unsigned short* __restrict__ Bt, int BN) {
    int o = blockIdx.x * 256 + threadIdx.x;
    if (o >= BN * 256) return;
    int k = o & 255, n = o >> 8;
    Bt[o] = f2bf(B[k * BN + n]);
}

// ---------------- aggregation: flat edge loop, quarter-wave per edge ----------------
// ed: {src|r<<16, fp32 w}. Per edge: one 8B sequential read + one 256B gather +
// ternary c[r]*w + 8 pk-FMAs. EXPLICIT SCALARS ONLY (r8/r9 spilled via arrays).
__global__ __launch_bounds__(256) void k_agg(const uint4* __restrict__ hb4,
                                             const int* __restrict__ rp2,
                                             const uint2* __restrict__ ed,
                                             const float* __restrict__ coeff,
                                             uint2* __restrict__ Mb2) {
    int wave = (blockIdx.x * 256 + threadIdx.x) >> 6;
    int lane = threadIdx.x & 63;
    if (wave >= NN) return;
    int q = lane >> 4, hl = lane & 15;

    float c00 = coeff[0], c01 = coeff[1], c10 = coeff[2], c11 = coeff[3];
    float c20 = coeff[4], c21 = coeff[5], c30 = coeff[6], c31 = coeff[7];

    f2 a0[4], a1[4];
#pragma unroll
    for (int i = 0; i < 4; i++) { a0[i] = (f2){0.f, 0.f}; a1[i] = (f2){0.f, 0.f}; }

    int e0 = rp2[wave * 4], e1 = rp2[wave * 4 + 4];

    int e = e0;
    // main: 8 edges/iter, 2 per quarter, 2 gathers in flight
    for (; e + 7 < e1; e += 8) {
        uint2 weA = ed[e + q];
        uint2 weB = ed[e + 4 + q];
        uint4 hA = hb4[(size_t)(weA.x & 0xFFFFu) * 16 + hl];
        uint4 hB = hb4[(size_t)(weB.x & 0xFFFFu) * 16 + hl];
        int rA = (int)(weA.x >> 16);
        int rB = (int)(weB.x >> 16);
        float wsA = __uint_as_float(weA.y);
        float wsB = __uint_as_float(weB.y);
        float wa0 = (rA == 0 ? c00 : rA == 1 ? c10 : rA == 2 ? c20 : c30) * wsA;
        float wa1 = (rA == 0 ? c01 : rA == 1 ? c11 : rA == 2 ? c21 : c31) * wsA;
        float wb0 = (rB == 0 ? c00 : rB == 1 ? c10 : rB == 2 ? c20 : c30) * wsB;
        float wb1 = (rB == 0 ? c01 : rB == 1 ? c11 : rB == 2 ? c21 : c31) * wsB;
        f2 vA0 = (f2){wa0, wa0}, vA1 = (f2){wa1, wa1};
        f2 vB0 = (f2){wb0, wb0}, vB1 = (f2){wb1, wb1};
        f2 h0, h1, h2, h3;
        h0 = (f2){__uint_as_float(hA.x << 16), __uint_as_float(hA.x & 0xFFFF0000u)};
        h1 = (f2){__uint_as_float(hA.y << 16), __uint_as_float(hA.y & 0xFFFF0000u)};
        h2 = (f2){__uint_as_float(hA.z << 16), __uint_as_float(hA.z & 0xFFFF0000u)};
        h3 = (f2){__uint_as_float(hA.w << 16), __uint_as_float(hA.w & 0xFFFF0000u)};
        a0[0] = __builtin_elementwise_fma(vA0, h0, a0[0]);
        a0[1] = __builtin_elementwise_fma(vA0, h1, a0[1]);
        a0[2] = __builtin_elementwise_fma(vA0, h2, a0[2]);
        a0[3] = __builtin_elementwise_fma(vA0, h3, a0[3]);
        a1[0] = __builtin_elementwise_fma(vA1, h0, a1[0]);
        a1[1] = __builtin_elementwise_fma(vA1, h1, a1[1]);
        a1[2] = __builtin_elementwise_fma(vA1, h2, a1[2]);
        a1[3] = __builtin_elementwise_fma(vA1, h3, a1[3]);
        h0 = (f2){__uint_as_float(hB.x << 16), __uint_as_float(hB.x & 0xFFFF0000u)};
        h1 = (f2){__uint_as_float(hB.y << 16), __uint_as_float(hB.y & 0xFFFF0000u)};
        h2 = (f2){__uint_as_float(hB.z << 16), __uint_as_float(hB.z & 0xFFFF0000u)};
        h3 = (f2){__uint_as_float(hB.w << 16), __uint_as_float(hB.w & 0xFFFF0000u)};
        a0[0] = __builtin_elementwise_fma(vB0, h0, a0[0]);
        a0[1] = __builtin_elementwise_fma(vB0, h1, a0[1]);
        a0[2] = __builtin_elementwise_fma(vB0, h2, a0[2]);
        a0[3] = __builtin_elementwise_fma(vB0, h3, a0[3]);
        a1[0] = __builtin_elementwise_fma(vB1, h0, a1[0]);
        a1[1] = __builtin_elementwise_fma(vB1, h1, a1[1]);
        a1[2] = __builtin_elementwise_fma(vB1, h2, a1[2]);
        a1[3] = __builtin_elementwise_fma(vB1, h3, a1[3]);
    }
    // masked tail: 4 edges/iter, one per quarter
    for (; e < e1; e += 4) {
        int E = e + q;
        bool act = E < e1;
        uint2 weA = ed[act ? E : e0];
        uint4 hA = hb4[(size_t)(weA.x & 0xFFFFu) * 16 + hl];
        int rA = (int)(weA.x >> 16);
        float wsA = act ? __uint_as_float(weA.y) : 0.f;
        float wa0 = (rA == 0 ? c00 : rA == 1 ? c10 : rA == 2 ? c20 : c30) * wsA;
        float wa1 = (rA == 0 ? c01 : rA == 1 ? c11 : rA == 2 ? c21 : c31) * wsA;
        f2 vA0 = (f2){wa0, wa0}, vA1 = (f2){wa1, wa1};
        f2 h0, h1, h2, h3;
        h0 = (f2){__uint_as_float(hA.x << 16), __uint_as_float(hA.x & 0xFFFF0000u)};
        h1 = (f2){__uint_as_float(hA.y << 16), __uint_as_float(hA.y & 0xFFFF0000u)};
        h2 = (f2){__uint_as_float(hA.z << 16), __uint_as_float(hA.z & 0xFFFF0000u)};
        h3 = (f2){__uint_as_float(hA.w << 16), __uint_as_float(hA.w & 0xFFFF0000u)};
        a0[0] = __builtin_elementwise_fma(vA0, h0, a0[0]);
        a0[1] = __builtin_elementwise_fma(vA0, h1, a0[1]);
        a0[2] = __builtin_elementwise_fma(vA0, h2, a0[2]);
        a0[3] = __builtin_elementwise_fma(vA0, h3, a0[3]);
        a1[0] = __builtin_elementwise_fma(vA1, h0, a1[0]);
        a1[1] = __builtin_elementwise_fma(vA1, h1, a1[1]);
        a1[2] = __builtin_elementwise_fma(vA1, h2, a1[2]);
        a1[3] = __builtin_elementwise_fma(vA1, h3, a1[3]);
    }

    // cross-quarter reduce (xor 16, then 32): all quarters end with full sums
#pragma unroll
    for (int i = 0; i < 4; i++) {
        a0[i].x += __shfl_xor(a0[i].x, 16, 64); a0[i].x += __shfl_xor(a0[i].x, 32, 64);
        a0[i].y += __shfl_xor(a0[i].y, 16, 64); a0[i].y += __shfl_xor(a0[i].y, 32, 64);
        a1[i].x += __shfl_xor(a1[i].x, 16, 64); a1[i].x += __shfl_xor(a1[i].x, 32, 64);
        a1[i].y += __shfl_xor(a1[i].y, 16, 64); a1[i].y += __shfl_xor(a1[i].y, 32, 64);
    }

    // lane (q,hl): coeff c = q>>1, half h4 = q&1 -> channels hl*8 + h4*4 + 0..3
    int c = q >> 1, h4 = q & 1;
    f2 p0 = c ? a1[h4 * 2] : a0[h4 * 2];
    f2 p1 = c ? a1[h4 * 2 + 1] : a0[h4 * 2 + 1];
    uint2 st;
    st.x = pack2(p0.x, p0.y);
    st.y = pack2(p1.x, p1.y);
    Mb2[(size_t)wave * 64 + c * 32 + hl * 2 + h4] = st;
}

// ---------------- MFMA bf16 GEMM: C[N,BN] = Mb[N,256] @ B[256,BN] ----------------
template <int BN, bool BF16OUT>
__global__ __launch_bounds__(256) void k_gemm(const unsigned short* __restrict__ A,
                                              const unsigned short* __restrict__ Bt,
                                              void* __restrict__ Cout) {
    int wave = threadIdx.x >> 6, lane = threadIdx.x & 63;
    int row0 = blockIdx.x * 64 + wave * 16;
    if (row0 >= NN) return;
    int m = lane & 15, q = lane >> 4;
    const int NT = BN / 16;

    frag_cd acc[NT];
#pragma unroll
    for (int ct = 0; ct < NT; ct++) acc[ct] = (frag_cd){0.f, 0.f, 0.f, 0.f};

    const size_t abase = (size_t)(row0 + m) * 256 + q * 8;
#pragma unroll
    for (int kc = 0; kc < 8; kc++) {
        frag_ab a = *(const frag_ab*)(A + abase + kc * 32);
#pragma unroll
        for (int ct = 0; ct < NT; ct++) {
            frag_ab b = *(const frag_ab*)(Bt + (size_t)(ct * 16 + m) * 256 + kc * 32 + q * 8);
            acc[ct] = __builtin_amdgcn_mfma_f32_16x16x32_bf16(a, b, acc[ct], 0, 0, 0);
        }
    }

#pragma unroll
    for (int ct = 0; ct < NT; ct++) {
#pragma unroll
        for (int i = 0; i < 4; i++) {
            int row = row0 + q * 4 + i;
            int col = ct * 16 + m;
            float v = acc[ct][i];
            if (BF16OUT) {
                v = fmaxf(v, 0.f);
                ((unsigned short*)Cout)[(size_t)row * BN + col] = f2bf(v);
            } else {
                ((float*)Cout)[(size_t)row * BN + col] = v;
            }
        }
    }
}

// ---------------- host ----------------

extern "C" void kernel_launch(void* const* d_in, const int* in_sizes, int n_in,
                              void* d_out, int out_size, void* d_ws, size_t ws_size,
                              hipStream_t stream) {
    const float* x      = (const float*)d_in[0];
    const int*   src    = (const int*)d_in[1];
    const int*   dst    = (const int*)d_in[2];
    const float* basis0 = (const float*)d_in[3];
    const float* coeff0 = (const float*)d_in[4];
    const float* basis1 = (const float*)d_in[5];
    const float* coeff1 = (const float*)d_in[6];
    const float* basis2 = (const float*)d_in[7];
    const float* coeff2 = (const float*)d_in[8];
    float* out = (float*)d_out;

    char* p = (char*)d_ws;
    auto alloc = [&](size_t bytes) {
        char* r = p;
        p += (bytes + 255) & ~(size_t)255;
        return r;
    };
    int*   cnt_srcQ = (int*)alloc((size_t)4 * RN * 4);
    int*   cnt_dstQ = (int*)alloc((size_t)4 * RN * 4);
    float* nsrc     = (float*)alloc((size_t)RN * 4);
    float* ndst     = (float*)alloc((size_t)RN * 4);
    int*   cntd2    = (int*)alloc((size_t)NSEG * 4);
    int*   rp2      = (int*)alloc((size_t)(NSEG + 1) * 4);
    int*   part     = (int*)alloc((size_t)SCB2 * 4);
    int*   offs     = (int*)alloc((size_t)SCB2 * 4);
    int*   gcur     = (int*)alloc((size_t)NBK * 4);
    unsigned* stage = (unsigned*)alloc((size_t)TE * 4);
    uint2* ed       = (uint2*)alloc((size_t)TE * 8);
    unsigned* Mb   = (unsigned*)alloc((size_t)NN * 128 * 4);        // bf16 [N][256]
    unsigned* Hb   = (unsigned*)alloc((size_t)NN * 64 * 4);         // bf16 [N][128]
    unsigned* Xb   = (unsigned*)alloc((size_t)NN * 64 * 4);         // bf16 [N][128]
    unsigned short* Bt0 = (unsigned short*)alloc((size_t)128 * 256 * 2);
    unsigned short* Bt1 = (unsigned short*)alloc((size_t)128 * 256 * 2);
    unsigned short* Bt2 = (unsigned short*)alloc((size_t)64 * 256 * 2);

    // setup
    k_cvt_x<<<(NN * 32 + 255) / 256, 256, 0, stream>>>((const float4*)x, (uint2*)Xb, NN * 32);
    k_cvt_bt<<<(128 * 256 + 255) / 256, 256, 0, stream>>>(basis0, Bt0, 128);
    k_cvt_bt<<<(128 * 256 + 255) / 256, 256, 0, stream>>>(basis1, Bt1, 128);
    k_cvt_bt<<<(64 * 256 + 255) / 256, 256, 0, stream>>>(basis2, Bt2, 64);
    k_hist<<<128, 1024, 0, stream>>>(src, dst, cnt_srcQ, cnt_dstQ);
    k_sum_norms<<<(RN + 255) / 256, 256, 0, stream>>>(cnt_srcQ, cnt_dstQ, nsrc, ndst, cntd2);
    k_partial<<<SCB2, 256, 0, stream>>>(cntd2, part);
    k_scan_small<<<1, 1024, 0, stream>>>(part, offs);
    k_emit<<<SCB2, 256, 0, stream>>>(cntd2, offs, rp2);
    k_initg<<<(NBK + 255) / 256, 256, 0, stream>>>(rp2, gcur);
    k_fillA<<<dim3(EE / CHA, RR), 256, 0, stream>>>(src, dst, gcur, stage);
    k_fillB<<<NBK, 256, 0, stream>>>(stage, rp2, nsrc, ndst, ed);

    int aggBlocks = NN / 4;
    int gemmBlocks = (NN + 63) / 64;   // 782

    // layer 0: Xb -> Mb -> Hb (relu, bf16)
    k_agg<<<aggBlocks, 256, 0, stream>>>((const uint4*)Xb, rp2, ed, coeff0, (uint2*)Mb);
    k_gemm<128, true><<<gemmBlocks, 256, 0, stream>>>((const unsigned short*)Mb, Bt0, Hb);
    // layer 1
    k_agg<<<aggBlocks, 256, 0, stream>>>((const uint4*)Hb, rp2, ed, coeff1, (uint2*)Mb);
    k_gemm<128, true><<<gemmBlocks, 256, 0, stream>>>((const unsigned short*)Mb, Bt1, Hb);
    // layer 2: final, fp32 out, no relu
    k_agg<<<aggBlocks, 256, 0, stream>>>((const uint4*)Hb, rp2, ed, coeff2, (uint2*)Mb);
    k_gemm<64, false><<<gemmBlocks, 256, 0, stream>>>((const unsigned short*)Mb, Bt2, out);
}

// Round 11
// 415.071 us; speedup vs baseline: 1.6730x; 1.4414x over previous
//
#include <hip/hip_runtime.h>
#include <hip/hip_bf16.h>
#include <cstdint>
#include <cstddef>

#define NN 50000
#define RR 4
#define EE 400000
#define TE (RR*EE)
#define HR 12500         // hist bins per range (4 ranges * 12500 = 50000)
#define RN (RR*NN)       // 200000
#define NSEG (NN*RR)     // 200000 (d-major, r-minor segments)
#define SCB2 782         // ceil(NSEG/256)
#define NBK 512          // dst buckets for the partition
#define BKSZ 98          // nodes per bucket (512*98 >= 50000)
#define CHA 4000         // edges per phase-A block (100 chunks/relation)
#define MAXSPAN 4608     // LDS image capacity (avg span ~3136)

using frag_ab = __attribute__((ext_vector_type(8))) short;   // 8 bf16 (4 VGPRs)
using frag_cd = __attribute__((ext_vector_type(4))) float;   // 4 fp32

static __device__ __forceinline__ unsigned short f2bf(float f) {
    union { float f; unsigned u; } v; v.f = f;
    unsigned r = (v.u + 0x7FFF + ((v.u >> 16) & 1)) >> 16;   // RNE
    return (unsigned short)r;
}
static __device__ __forceinline__ unsigned pack2(float lo, float hi) {
    return (unsigned)f2bf(lo) | ((unsigned)f2bf(hi) << 16);
}
static __device__ __forceinline__ float blo(unsigned u) { return __uint_as_float(u << 16); }
static __device__ __forceinline__ float bhi(unsigned u) { return __uint_as_float(u & 0xFFFF0000u); }

// ---------------- degree histograms: packed 16-bit LDS counters ----------------
__global__ __launch_bounds__(1024) void k_hist(const int* __restrict__ src,
                                               const int* __restrict__ dst,
                                               int* __restrict__ cnt_srcQ,
                                               int* __restrict__ cnt_dstQ) {
    __shared__ unsigned bins[HR / 2];   // 6250 uints = 25 KB
    int combo = blockIdx.x >> 4;
    int range = (blockIdx.x >> 2) & 3;
    int qc    = blockIdx.x & 3;
    int r = combo >> 1;
    int side = combo & 1;
    const int* arr = (side == 0 ? src : dst) + (size_t)r * EE + (size_t)qc * (EE / 4);
    int lo = range * HR;
    for (int i = threadIdx.x; i < HR / 2; i += 1024) bins[i] = 0;
    __syncthreads();
    const int4* a4 = (const int4*)arr;
    for (int i = threadIdx.x; i < EE / 16; i += 1024) {
        int4 v = a4[i];
        int t;
        t = v.x - lo; if ((unsigned)t < (unsigned)HR) atomicAdd(&bins[t >> 1], 1u << ((t & 1) * 16));
        t = v.y - lo; if ((unsigned)t < (unsigned)HR) atomicAdd(&bins[t >> 1], 1u << ((t & 1) * 16));
        t = v.z - lo; if ((unsigned)t < (unsigned)HR) atomicAdd(&bins[t >> 1], 1u << ((t & 1) * 16));
        t = v.w - lo; if ((unsigned)t < (unsigned)HR) atomicAdd(&bins[t >> 1], 1u << ((t & 1) * 16));
    }
    __syncthreads();
    int* outp = (side == 0 ? cnt_srcQ : cnt_dstQ) + (size_t)qc * RN + (size_t)r * NN + lo;
    for (int i = threadIdx.x; i < HR / 2; i += 1024) {
        unsigned b = bins[i];
        outp[2 * i]     = (int)(b & 0xFFFFu);
        outp[2 * i + 1] = (int)(b >> 16);
    }
}

// sum quarters -> norms ([r*NN+d]) + counts in [d*4+r] layout for the scan
__global__ __launch_bounds__(256) void k_sum_norms(const int* __restrict__ cnt_srcQ,
                                                   const int* __restrict__ cnt_dstQ,
                                                   float* __restrict__ nsrc,
                                                   float* __restrict__ ndst,
                                                   int* __restrict__ cntd2) {
    int i = blockIdx.x * 256 + threadIdx.x;
    if (i >= RN) return;
    int ss = cnt_srcQ[i] + cnt_srcQ[RN + i] + cnt_srcQ[2 * RN + i] + cnt_srcQ[3 * RN + i];
    int ds = cnt_dstQ[i] + cnt_dstQ[RN + i] + cnt_dstQ[2 * RN + i] + cnt_dstQ[3 * RN + i];
    nsrc[i] = 1.0f / sqrtf(fmaxf((float)ss, 1.0f));
    ndst[i] = 1.0f / sqrtf(fmaxf((float)ds, 1.0f));
    int r = i / NN, d = i - r * NN;
    cntd2[d * 4 + r] = ds;
}

// ---------------- 3-phase parallel scan over 200K (d,r) segment counts ----------------
__global__ __launch_bounds__(256) void k_partial(const int* __restrict__ cntd2,
                                                 int* __restrict__ part) {
    __shared__ int s[256];
    int t = threadIdx.x;
    int f = blockIdx.x * 256 + t;
    int v = (f < NSEG) ? cntd2[f] : 0;
    s[t] = v;
    __syncthreads();
    for (int off = 128; off > 0; off >>= 1) {
        if (t < off) s[t] += s[t + off];
        __syncthreads();
    }
    if (t == 0) part[blockIdx.x] = s[0];
}

__global__ __launch_bounds__(1024) void k_scan_small(const int* __restrict__ part,
                                                     int* __restrict__ offs) {
    __shared__ int s[1024];
    int t = threadIdx.x;
    s[t] = (t < SCB2) ? part[t] : 0;
    __syncthreads();
    for (int off = 1; off < 1024; off <<= 1) {
        int v = (t >= off) ? s[t - off] : 0;
        __syncthreads();
        s[t] += v;
        __syncthreads();
    }
    if (t < SCB2) offs[t] = (t == 0) ? 0 : s[t - 1];
}

__global__ __launch_bounds__(256) void k_emit(const int* __restrict__ cntd2,
                                              const int* __restrict__ offs,
                                              int* __restrict__ rp2) {
    __shared__ int s[256];
    int t = threadIdx.x;
    int f = blockIdx.x * 256 + t;
    int v = (f < NSEG) ? cntd2[f] : 0;
    s[t] = v;
    __syncthreads();
    for (int off = 1; off < 256; off <<= 1) {
        int u = (t >= off) ? s[t - off] : 0;
        __syncthreads();
        s[t] += u;
        __syncthreads();
    }
    if (f < NSEG) rp2[f] = offs[blockIdx.x] + s[t] - v;
    if (f == NSEG - 1) rp2[NSEG] = TE;
}

// ---------------- two-phase edge partition ----------------
__global__ __launch_bounds__(256) void k_initg(const int* __restrict__ rp2,
                                               int* __restrict__ gcur) {
    int i = blockIdx.x * 256 + threadIdx.x;
    if (i < NBK) gcur[i] = rp2[min(i * BKSZ * 4, NSEG)];
}

// Phase A: multi-split edges into 512 dst-range buckets.
// payload: src(16) | r(2 @16) | dlocal(7 @18)
__global__ __launch_bounds__(256) void k_fillA(const int* __restrict__ src,
                                               const int* __restrict__ dst,
                                               int* __restrict__ gcur,
                                               unsigned* __restrict__ stage) {
    __shared__ int cnt[NBK];
    __shared__ int rcur[NBK];
    int r = blockIdx.y;
    int base_e = blockIdx.x * CHA;
    int t = threadIdx.x;
    for (int i = t; i < NBK; i += 256) cnt[i] = 0;
    __syncthreads();
    const int* dr = dst + (size_t)r * EE;
    const int* sr = src + (size_t)r * EE;
    for (int i = base_e + t; i < base_e + CHA; i += 256) {
        int d = dr[i];
        atomicAdd(&cnt[d / BKSZ], 1);
    }
    __syncthreads();
    for (int i = t; i < NBK; i += 256) rcur[i] = atomicAdd(&gcur[i], cnt[i]);
    __syncthreads();
    for (int i = base_e + t; i < base_e + CHA; i += 256) {
        int d = dr[i];
        int s = sr[i];
        int b = d / BKSZ;
        int dl = d - b * BKSZ;
        int pos = atomicAdd(&rcur[b], 1);
        stage[pos] = (unsigned)s | ((unsigned)r << 16) | ((unsigned)dl << 18);
    }
}

// Phase B: one block per bucket; order into exact (d,r) segments via LDS image
// and emit the 8B edge record {src|r<<16, fp32 w=ns*nd} (layer-invariant).
__global__ __launch_bounds__(256) void k_fillB(const unsigned* __restrict__ stage,
                                               const int* __restrict__ rp2,
                                               const float* __restrict__ nsrc,
                                               const float* __restrict__ ndst,
                                               uint2* __restrict__ ed) {
    __shared__ unsigned imgU[MAXSPAN];   // src | r<<16
    __shared__ float imgW[MAXSPAN];      // ns*nd
    __shared__ int lcur[BKSZ * 4];
    __shared__ float ndL[BKSZ * 4];
    int b = blockIdx.x;
    int t = threadIdx.x;
    int node0 = b * BKSZ;
    if (node0 >= NN) return;
    int nodes = min(BKSZ, NN - node0);
    int nseg_local = nodes * 4;
    int segbase = node0 * 4;
    for (int i = t; i < nseg_local; i += 256) {
        lcur[i] = rp2[segbase + i];
        ndL[i] = ndst[(i & 3) * NN + node0 + (i >> 2)];
    }
    __syncthreads();
    int S0 = rp2[segbase];
    int S1 = rp2[segbase + nseg_local];
    int span = S1 - S0;
    if (span <= MAXSPAN) {
        for (int i = S0 + t; i < S1; i += 256) {
            unsigned w = stage[i];
            int s = (int)(w & 0xFFFFu);
            int r = (int)((w >> 16) & 3u);
            int dl = (int)(w >> 18);
            int seg = dl * 4 + r;
            int pos = atomicAdd(&lcur[seg], 1);
            int idx = pos - S0;
            imgU[idx] = w & 0x3FFFFu;            // src | r<<16
            imgW[idx] = nsrc[r * NN + s] * ndL[seg];
        }
        __syncthreads();
        for (int i = t; i < span; i += 256)
            ed[S0 + i] = make_uint2(imgU[i], __float_as_uint(imgW[i]));
    } else {  // overflow fallback (statistically unreachable)
        for (int i = S0 + t; i < S1; i += 256) {
            unsigned w = stage[i];
            int s = (int)(w & 0xFFFFu);
            int r = (int)((w >> 16) & 3u);
            int dl = (int)(w >> 18);
            int seg = dl * 4 + r;
            int pos = atomicAdd(&lcur[seg], 1);
            ed[pos] = make_uint2(w & 0x3FFFFu,
                                 __float_as_uint(nsrc[r * NN + s] * ndL[seg]));
        }
    }
}

// ---------------- converts ----------------
__global__ __launch_bounds__(256) void k_cvt_x(const float4* __restrict__ x4,
                                               uint2* __restrict__ o, int n4) {
    int i = blockIdx.x * 256 + threadIdx.x;
    if (i >= n4) return;
    float4 v = x4[i];
    o[i] = make_uint2(pack2(v.x, v.y), pack2(v.z, v.w));
}

// Bt[n][k] = bf16(basis[k][n]); basis flat [256][BN]
__global__ __launch_bounds__(256) void k_cvt_bt(const float* __restrict__ B,
                                                unsigned short* __restrict__ Bt, int BN) {
    int o = blockIdx.x * 256 + threadIdx.x;
    if (o >= BN * 256) return;
    int k = o & 255, n = o >> 8;
    Bt[o] = f2bf(B[k * BN + n]);
}

// ---------------- aggregation: flat edge loop, quarter-wave per edge ----------------
// ed: {src|r<<16, fp32 w}. NAMED SCALAR accumulators ONLY — f2 ext-vector arrays
// (r8/r9/r10) defeated SROA and lived in scratch: WRITE_SIZE 392-598 MB of
// L2-evicted scratch traffic. Scalars (r6/r7 codegen) stay in VGPRs.
__global__ __launch_bounds__(256) void k_agg(const uint4* __restrict__ hb4,
                                             const int* __restrict__ rp2,
                                             const uint2* __restrict__ ed,
                                             const float* __restrict__ coeff,
                                             uint2* __restrict__ Mb2) {
    int wave = (blockIdx.x * 256 + threadIdx.x) >> 6;
    int lane = threadIdx.x & 63;
    if (wave >= NN) return;
    int q = lane >> 4, hl = lane & 15;

    float c00 = coeff[0], c01 = coeff[1], c10 = coeff[2], c11 = coeff[3];
    float c20 = coeff[4], c21 = coeff[5], c30 = coeff[6], c31 = coeff[7];

    float a00 = 0.f, a01 = 0.f, a02 = 0.f, a03 = 0.f;
    float a04 = 0.f, a05 = 0.f, a06 = 0.f, a07 = 0.f;
    float a10 = 0.f, a11 = 0.f, a12 = 0.f, a13 = 0.f;
    float a14 = 0.f, a15 = 0.f, a16 = 0.f, a17 = 0.f;

    int e0 = rp2[wave * 4], e1 = rp2[wave * 4 + 4];

    int e = e0;
    // main: 8 edges/iter, 2 per quarter, 2 gathers in flight
    for (; e + 7 < e1; e += 8) {
        uint2 weA = ed[e + q];
        uint2 weB = ed[e + 4 + q];
        uint4 hA = hb4[(size_t)(weA.x & 0xFFFFu) * 16 + hl];
        uint4 hB = hb4[(size_t)(weB.x & 0xFFFFu) * 16 + hl];
        int rA = (int)(weA.x >> 16);
        int rB = (int)(weB.x >> 16);
        float wsA = __uint_as_float(weA.y);
        float wsB = __uint_as_float(weB.y);
        float wa0 = (rA == 0 ? c00 : rA == 1 ? c10 : rA == 2 ? c20 : c30) * wsA;
        float wa1 = (rA == 0 ? c01 : rA == 1 ? c11 : rA == 2 ? c21 : c31) * wsA;
        float wb0 = (rB == 0 ? c00 : rB == 1 ? c10 : rB == 2 ? c20 : c30) * wsB;
        float wb1 = (rB == 0 ? c01 : rB == 1 ? c11 : rB == 2 ? c21 : c31) * wsB;

        float h0 = blo(hA.x), h1 = bhi(hA.x), h2 = blo(hA.y), h3 = bhi(hA.y);
        float h4 = blo(hA.z), h5 = bhi(hA.z), h6 = blo(hA.w), h7 = bhi(hA.w);
        a00 += wa0 * h0; a01 += wa0 * h1; a02 += wa0 * h2; a03 += wa0 * h3;
        a04 += wa0 * h4; a05 += wa0 * h5; a06 += wa0 * h6; a07 += wa0 * h7;
        a10 += wa1 * h0; a11 += wa1 * h1; a12 += wa1 * h2; a13 += wa1 * h3;
        a14 += wa1 * h4; a15 += wa1 * h5; a16 += wa1 * h6; a17 += wa1 * h7;

        h0 = blo(hB.x); h1 = bhi(hB.x); h2 = blo(hB.y); h3 = bhi(hB.y);
        h4 = blo(hB.z); h5 = bhi(hB.z); h6 = blo(hB.w); h7 = bhi(hB.w);
        a00 += wb0 * h0; a01 += wb0 * h1; a02 += wb0 * h2; a03 += wb0 * h3;
        a04 += wb0 * h4; a05 += wb0 * h5; a06 += wb0 * h6; a07 += wb0 * h7;
        a10 += wb1 * h0; a11 += wb1 * h1; a12 += wb1 * h2; a13 += wb1 * h3;
        a14 += wb1 * h4; a15 += wb1 * h5; a16 += wb1 * h6; a17 += wb1 * h7;
    }
    // masked tail: 4 edges/iter, one per quarter
    for (; e < e1; e += 4) {
        int E = e + q;
        bool act = E < e1;
        uint2 weA = ed[act ? E : e0];
        uint4 hA = hb4[(size_t)(weA.x & 0xFFFFu) * 16 + hl];
        int rA = (int)(weA.x >> 16);
        float wsA = act ? __uint_as_float(weA.y) : 0.f;
        float wa0 = (rA == 0 ? c00 : rA == 1 ? c10 : rA == 2 ? c20 : c30) * wsA;
        float wa1 = (rA == 0 ? c01 : rA == 1 ? c11 : rA == 2 ? c21 : c31) * wsA;
        float h0 = blo(hA.x), h1 = bhi(hA.x), h2 = blo(hA.y), h3 = bhi(hA.y);
        float h4 = blo(hA.z), h5 = bhi(hA.z), h6 = blo(hA.w), h7 = bhi(hA.w);
        a00 += wa0 * h0; a01 += wa0 * h1; a02 += wa0 * h2; a03 += wa0 * h3;
        a04 += wa0 * h4; a05 += wa0 * h5; a06 += wa0 * h6; a07 += wa0 * h7;
        a10 += wa1 * h0; a11 += wa1 * h1; a12 += wa1 * h2; a13 += wa1 * h3;
        a14 += wa1 * h4; a15 += wa1 * h5; a16 += wa1 * h6; a17 += wa1 * h7;
    }

    // cross-quarter reduce (xor 16, then 32): all quarters end with full sums
    a00 += __shfl_xor(a00, 16, 64); a00 += __shfl_xor(a00, 32, 64);
    a01 += __shfl_xor(a01, 16, 64); a01 += __shfl_xor(a01, 32, 64);
    a02 += __shfl_xor(a02, 16, 64); a02 += __shfl_xor(a02, 32, 64);
    a03 += __shfl_xor(a03, 16, 64); a03 += __shfl_xor(a03, 32, 64);
    a04 += __shfl_xor(a04, 16, 64); a04 += __shfl_xor(a04, 32, 64);
    a05 += __shfl_xor(a05, 16, 64); a05 += __shfl_xor(a05, 32, 64);
    a06 += __shfl_xor(a06, 16, 64); a06 += __shfl_xor(a06, 32, 64);
    a07 += __shfl_xor(a07, 16, 64); a07 += __shfl_xor(a07, 32, 64);
    a10 += __shfl_xor(a10, 16, 64); a10 += __shfl_xor(a10, 32, 64);
    a11 += __shfl_xor(a11, 16, 64); a11 += __shfl_xor(a11, 32, 64);
    a12 += __shfl_xor(a12, 16, 64); a12 += __shfl_xor(a12, 32, 64);
    a13 += __shfl_xor(a13, 16, 64); a13 += __shfl_xor(a13, 32, 64);
    a14 += __shfl_xor(a14, 16, 64); a14 += __shfl_xor(a14, 32, 64);
    a15 += __shfl_xor(a15, 16, 64); a15 += __shfl_xor(a15, 32, 64);
    a16 += __shfl_xor(a16, 16, 64); a16 += __shfl_xor(a16, 32, 64);
    a17 += __shfl_xor(a17, 16, 64); a17 += __shfl_xor(a17, 32, 64);

    // lane (q,hl): coeff c = q>>1, half h4 = q&1 -> channels hl*8 + h4*4 + 0..3
    int c = q >> 1, h4 = q & 1;
    float v0 = c ? (h4 ? a14 : a10) : (h4 ? a04 : a00);
    float v1 = c ? (h4 ? a15 : a11) : (h4 ? a05 : a01);
    float v2 = c ? (h4 ? a16 : a12) : (h4 ? a06 : a02);
    float v3 = c ? (h4 ? a17 : a13) : (h4 ? a07 : a03);
    uint2 st;
    st.x = pack2(v0, v1);
    st.y = pack2(v2, v3);
    Mb2[(size_t)wave * 64 + c * 32 + hl * 2 + h4] = st;
}

// ---------------- MFMA bf16 GEMM: C[N,BN] = Mb[N,256] @ B[256,BN] ----------------
template <int BN, bool BF16OUT>
__global__ __launch_bounds__(256) void k_gemm(const unsigned short* __restrict__ A,
                                              const unsigned short* __restrict__ Bt,
                                              void* __restrict__ Cout) {
    int wave = threadIdx.x >> 6, lane = threadIdx.x & 63;
    int row0 = blockIdx.x * 64 + wave * 16;
    if (row0 >= NN) return;
    int m = lane & 15, q = lane >> 4;
    const int NT = BN / 16;

    frag_cd acc[NT];
#pragma unroll
    for (int ct = 0; ct < NT; ct++) acc[ct] = (frag_cd){0.f, 0.f, 0.f, 0.f};

    const size_t abase = (size_t)(row0 + m) * 256 + q * 8;
#pragma unroll
    for (int kc = 0; kc < 8; kc++) {
        frag_ab a = *(const frag_ab*)(A + abase + kc * 32);
#pragma unroll
        for (int ct = 0; ct < NT; ct++) {
            frag_ab b = *(const frag_ab*)(Bt + (size_t)(ct * 16 + m) * 256 + kc * 32 + q * 8);
            acc[ct] = __builtin_amdgcn_mfma_f32_16x16x32_bf16(a, b, acc[ct], 0, 0, 0);
        }
    }

#pragma unroll
    for (int ct = 0; ct < NT; ct++) {
#pragma unroll
        for (int i = 0; i < 4; i++) {
            int row = row0 + q * 4 + i;
            int col = ct * 16 + m;
            float v = acc[ct][i];
            if (BF16OUT) {
                v = fmaxf(v, 0.f);
                ((unsigned short*)Cout)[(size_t)row * BN + col] = f2bf(v);
            } else {
                ((float*)Cout)[(size_t)row * BN + col] = v;
            }
        }
    }
}

// ---------------- host ----------------

extern "C" void kernel_launch(void* const* d_in, const int* in_sizes, int n_in,
                              void* d_out, int out_size, void* d_ws, size_t ws_size,
                              hipStream_t stream) {
    const float* x      = (const float*)d_in[0];
    const int*   src    = (const int*)d_in[1];
    const int*   dst    = (const int*)d_in[2];
    const float* basis0 = (const float*)d_in[3];
    const float* coeff0 = (const float*)d_in[4];
    const float* basis1 = (const float*)d_in[5];
    const float* coeff1 = (const float*)d_in[6];
    const float* basis2 = (const float*)d_in[7];
    const float* coeff2 = (const float*)d_in[8];
    float* out = (float*)d_out;

    char* p = (char*)d_ws;
    auto alloc = [&](size_t bytes) {
        char* r = p;
        p += (bytes + 255) & ~(size_t)255;
        return r;
    };
    int*   cnt_srcQ = (int*)alloc((size_t)4 * RN * 4);
    int*   cnt_dstQ = (int*)alloc((size_t)4 * RN * 4);
    float* nsrc     = (float*)alloc((size_t)RN * 4);
    float* ndst     = (float*)alloc((size_t)RN * 4);
    int*   cntd2    = (int*)alloc((size_t)NSEG * 4);
    int*   rp2      = (int*)alloc((size_t)(NSEG + 1) * 4);
    int*   part     = (int*)alloc((size_t)SCB2 * 4);
    int*   offs     = (int*)alloc((size_t)SCB2 * 4);
    int*   gcur     = (int*)alloc((size_t)NBK * 4);
    unsigned* stage = (unsigned*)alloc((size_t)TE * 4);
    uint2* ed       = (uint2*)alloc((size_t)TE * 8);
    unsigned* Mb   = (unsigned*)alloc((size_t)NN * 128 * 4);        // bf16 [N][256]
    unsigned* Hb   = (unsigned*)alloc((size_t)NN * 64 * 4);         // bf16 [N][128]
    unsigned* Xb   = (unsigned*)alloc((size_t)NN * 64 * 4);         // bf16 [N][128]
    unsigned short* Bt0 = (unsigned short*)alloc((size_t)128 * 256 * 2);
    unsigned short* Bt1 = (unsigned short*)alloc((size_t)128 * 256 * 2);
    unsigned short* Bt2 = (unsigned short*)alloc((size_t)64 * 256 * 2);

    // setup
    k_cvt_x<<<(NN * 32 + 255) / 256, 256, 0, stream>>>((const float4*)x, (uint2*)Xb, NN * 32);
    k_cvt_bt<<<(128 * 256 + 255) / 256, 256, 0, stream>>>(basis0, Bt0, 128);
    k_cvt_bt<<<(128 * 256 + 255) / 256, 256, 0, stream>>>(basis1, Bt1, 128);
    k_cvt_bt<<<(64 * 256 + 255) / 256, 256, 0, stream>>>(basis2, Bt2, 64);
    k_hist<<<128, 1024, 0, stream>>>(src, dst, cnt_srcQ, cnt_dstQ);
    k_sum_norms<<<(RN + 255) / 256, 256, 0, stream>>>(cnt_srcQ, cnt_dstQ, nsrc, ndst, cntd2);
    k_partial<<<SCB2, 256, 0, stream>>>(cntd2, part);
    k_scan_small<<<1, 1024, 0, stream>>>(part, offs);
    k_emit<<<SCB2, 256, 0, stream>>>(cntd2, offs, rp2);
    k_initg<<<(NBK + 255) / 256, 256, 0, stream>>>(rp2, gcur);
    k_fillA<<<dim3(EE / CHA, RR), 256, 0, stream>>>(src, dst, gcur, stage);
    k_fillB<<<NBK, 256, 0, stream>>>(stage, rp2, nsrc, ndst, ed);

    int aggBlocks = NN / 4;
    int gemmBlocks = (NN + 63) / 64;   // 782

    // layer 0: Xb -> Mb -> Hb (relu, bf16)
    k_agg<<<aggBlocks, 256, 0, stream>>>((const uint4*)Xb, rp2, ed, coeff0, (uint2*)Mb);
    k_gemm<128, true><<<gemmBlocks, 256, 0, stream>>>((const unsigned short*)Mb, Bt0, Hb);
    // layer 1
    k_agg<<<aggBlocks, 256, 0, stream>>>((const uint4*)Hb, rp2, ed, coeff1, (uint2*)Mb);
    k_gemm<128, true><<<gemmBlocks, 256, 0, stream>>>((const unsigned short*)Mb, Bt1, Hb);
    // layer 2: final, fp32 out, no relu
    k_agg<<<aggBlocks, 256, 0, stream>>>((const uint4*)Hb, rp2, ed, coeff2, (uint2*)Mb);
    k_gemm<64, false><<<gemmBlocks, 256, 0, stream>>>((const unsigned short*)Mb, Bt2, out);
}